// Round 1
// baseline (2124.308 us; speedup 1.0000x reference)
//
#include <hip/hip_runtime.h>

#define CDIM  1024
#define NHEADS 16
#define DHEAD  64
#define BATCH  4
#define TSEQ   2048
#define NEG_BIG (-1e30f)

// ---------------- GEMM with bias: C[M,N] = A[M,K] @ W[K,N] + b[N] -----------
// BM=BN=64, BK=16, 256 threads, 4x4 micro-tile per thread.
__global__ __launch_bounds__(256)
void gemm_bias_kernel(const float* __restrict__ A, const float* __restrict__ W,
                      const float* __restrict__ bias, float* __restrict__ Cout,
                      int M, int N, int K)
{
    __shared__ float As[16][64];   // [k][m]
    __shared__ float Bs[16][64];   // [k][n]
    const int tid = threadIdx.x;
    const int n0 = blockIdx.x * 64;
    const int m0 = blockIdx.y * 64;
    const int i  = tid >> 4;        // 0..15  (row group)
    const int j  = tid & 15;        // 0..15  (col group)
    const int lm  = tid >> 2;       // 0..63  A-load row
    const int lc4 = (tid & 3) * 4;  // A-load k offset
    const int lk  = tid >> 4;       // 0..15  B-load k
    const int ln  = (tid & 15) * 4; // B-load n offset

    float acc[4][4] = {{0.f}};

    for (int k0 = 0; k0 < K; k0 += 16) {
        __syncthreads();
        float4 av = *reinterpret_cast<const float4*>(&A[(size_t)(m0 + lm) * K + k0 + lc4]);
        As[lc4 + 0][lm] = av.x;
        As[lc4 + 1][lm] = av.y;
        As[lc4 + 2][lm] = av.z;
        As[lc4 + 3][lm] = av.w;
        *reinterpret_cast<float4*>(&Bs[lk][ln]) =
            *reinterpret_cast<const float4*>(&W[(size_t)(k0 + lk) * N + n0 + ln]);
        __syncthreads();
        #pragma unroll
        for (int kk = 0; kk < 16; ++kk) {
            float4 a = *reinterpret_cast<const float4*>(&As[kk][i * 4]);
            float4 b = *reinterpret_cast<const float4*>(&Bs[kk][j * 4]);
            const float aa[4] = {a.x, a.y, a.z, a.w};
            const float bb[4] = {b.x, b.y, b.z, b.w};
            #pragma unroll
            for (int x = 0; x < 4; ++x)
                #pragma unroll
                for (int y = 0; y < 4; ++y)
                    acc[x][y] = fmaf(aa[x], bb[y], acc[x][y]);
        }
    }
    #pragma unroll
    for (int x = 0; x < 4; ++x) {
        float4 o;
        o.x = acc[x][0] + bias[n0 + j * 4 + 0];
        o.y = acc[x][1] + bias[n0 + j * 4 + 1];
        o.z = acc[x][2] + bias[n0 + j * 4 + 2];
        o.w = acc[x][3] + bias[n0 + j * 4 + 3];
        *reinterpret_cast<float4*>(&Cout[(size_t)(m0 + i * 4 + x) * N + n0 + j * 4]) = o;
    }
}

// ---------------- Flash-style causal attention ------------------------------
// One block per (b, h, 64-row q tile). 256 threads, 4x4 output micro-tile.
// LDS tiles padded to stride 68 floats: bank = (4*row + d) % 32 -> worst
// 2-way (free). Writes y in-place over the Q buffer (each block's q region
// is read only by itself, at block start).
__global__ __launch_bounds__(256)
void attn_kernel(const float* __restrict__ Q, const float* __restrict__ K,
                 const float* __restrict__ V, float* __restrict__ Y)
{
    __shared__ float qs[64][68];
    __shared__ float ks[64][68];
    __shared__ float vs[64][68];
    __shared__ float ps[64][68];
    __shared__ float m_s[64], l_s[64], alpha_s[64];

    const int tid = threadIdx.x;
    const int qt  = blockIdx.x;
    const int h   = blockIdx.y;
    const int b   = blockIdx.z;
    const size_t base = (size_t)b * TSEQ * CDIM + (size_t)h * DHEAD;
    const int i = tid >> 4;   // 0..15
    const int j = tid & 15;   // 0..15

    // load Q tile (pre-scaled by 1/sqrt(D) = 0.125)
    #pragma unroll
    for (int u = 0; u < 4; ++u) {
        int fi = tid + 256 * u;
        int r  = fi >> 4;
        int d  = (fi & 15) * 4;
        float4 qv = *reinterpret_cast<const float4*>(&Q[base + (size_t)(qt * 64 + r) * CDIM + d]);
        qs[r][d + 0] = qv.x * 0.125f;
        qs[r][d + 1] = qv.y * 0.125f;
        qs[r][d + 2] = qv.z * 0.125f;
        qs[r][d + 3] = qv.w * 0.125f;
    }
    if (tid < 64) { m_s[tid] = NEG_BIG; l_s[tid] = 0.f; }

    float O[4][4] = {{0.f}};

    for (int kt = 0; kt <= qt; ++kt) {
        __syncthreads();   // previous iteration's ps/vs consumers done; qs ready (1st iter)
        #pragma unroll
        for (int u = 0; u < 4; ++u) {
            int fi = tid + 256 * u;
            int r  = fi >> 4;
            int d  = (fi & 15) * 4;
            size_t g = base + (size_t)(kt * 64 + r) * CDIM + d;
            *reinterpret_cast<float4*>(&ks[r][d]) = *reinterpret_cast<const float4*>(&K[g]);
            *reinterpret_cast<float4*>(&vs[r][d]) = *reinterpret_cast<const float4*>(&V[g]);
        }
        __syncthreads();

        // S = (q * scale) . k^T  -> 4x4 per thread
        float sacc[4][4] = {{0.f}};
        for (int d4 = 0; d4 < 64; d4 += 4) {
            float4 qv[4], kv[4];
            #pragma unroll
            for (int a = 0; a < 4; ++a)
                qv[a] = *reinterpret_cast<const float4*>(&qs[i * 4 + a][d4]);
            #pragma unroll
            for (int c = 0; c < 4; ++c)
                kv[c] = *reinterpret_cast<const float4*>(&ks[j * 4 + c][d4]);
            #pragma unroll
            for (int a = 0; a < 4; ++a) {
                #pragma unroll
                for (int c = 0; c < 4; ++c) {
                    sacc[a][c] = fmaf(qv[a].x, kv[c].x, sacc[a][c]);
                    sacc[a][c] = fmaf(qv[a].y, kv[c].y, sacc[a][c]);
                    sacc[a][c] = fmaf(qv[a].z, kv[c].z, sacc[a][c]);
                    sacc[a][c] = fmaf(qv[a].w, kv[c].w, sacc[a][c]);
                }
            }
        }
        if (kt == qt) {   // causal mask inside the diagonal tile
            #pragma unroll
            for (int a = 0; a < 4; ++a)
                #pragma unroll
                for (int c = 0; c < 4; ++c)
                    if (j * 4 + c > i * 4 + a) sacc[a][c] = NEG_BIG;
        }
        #pragma unroll
        for (int a = 0; a < 4; ++a) {
            float4 o;
            o.x = sacc[a][0]; o.y = sacc[a][1]; o.z = sacc[a][2]; o.w = sacc[a][3];
            *reinterpret_cast<float4*>(&ps[i * 4 + a][j * 4]) = o;
        }
        __syncthreads();

        // online softmax update: one lane per q row (wave 0)
        if (tid < 64) {
            const int r = tid;
            float mo = m_s[r];
            float mx = mo;
            for (int s = 0; s < 64; ++s) mx = fmaxf(mx, ps[r][s]);
            float alpha = __expf(mo - mx);
            float l = l_s[r] * alpha;
            for (int s = 0; s < 64; ++s) {
                float p = __expf(ps[r][s] - mx);
                ps[r][s] = p;
                l += p;
            }
            m_s[r] = mx; l_s[r] = l; alpha_s[r] = alpha;
        }
        __syncthreads();

        // O = O*alpha + P @ V
        #pragma unroll
        for (int a = 0; a < 4; ++a) {
            float al = alpha_s[i * 4 + a];
            #pragma unroll
            for (int c = 0; c < 4; ++c) O[a][c] *= al;
        }
        for (int s4 = 0; s4 < 64; s4 += 4) {
            float4 pv[4], vv[4];
            #pragma unroll
            for (int a = 0; a < 4; ++a)
                pv[a] = *reinterpret_cast<const float4*>(&ps[i * 4 + a][s4]);
            #pragma unroll
            for (int ss = 0; ss < 4; ++ss)
                vv[ss] = *reinterpret_cast<const float4*>(&vs[s4 + ss][j * 4]);
            #pragma unroll
            for (int a = 0; a < 4; ++a) {
                const float pa[4] = {pv[a].x, pv[a].y, pv[a].z, pv[a].w};
                #pragma unroll
                for (int ss = 0; ss < 4; ++ss) {
                    const float vb[4] = {vv[ss].x, vv[ss].y, vv[ss].z, vv[ss].w};
                    #pragma unroll
                    for (int c = 0; c < 4; ++c)
                        O[a][c] = fmaf(pa[ss], vb[c], O[a][c]);
                }
            }
        }
    }

    // epilogue: normalize and store (in-place over Q buffer region)
    #pragma unroll
    for (int a = 0; a < 4; ++a) {
        float inv = 1.0f / l_s[i * 4 + a];
        float4 o;
        o.x = O[a][0] * inv; o.y = O[a][1] * inv;
        o.z = O[a][2] * inv; o.w = O[a][3] * inv;
        *reinterpret_cast<float4*>(&Y[base + (size_t)(qt * 64 + i * 4 + a) * CDIM + j * 4]) = o;
    }
}

// ---------------------------------------------------------------------------
extern "C" void kernel_launch(void* const* d_in, const int* in_sizes, int n_in,
                              void* d_out, int out_size, void* d_ws, size_t ws_size,
                              hipStream_t stream)
{
    const float* x  = (const float*)d_in[0];
    const float* Wk = (const float*)d_in[1];
    const float* bk = (const float*)d_in[2];
    const float* Wq = (const float*)d_in[3];
    const float* bq = (const float*)d_in[4];
    const float* Wv = (const float*)d_in[5];
    const float* bv = (const float*)d_in[6];
    const float* Wp = (const float*)d_in[7];
    const float* bp = (const float*)d_in[8];
    float* out = (float*)d_out;

    const size_t bufElems = (size_t)BATCH * TSEQ * CDIM;  // 8,388,608 floats
    float* qb = (float*)d_ws;
    float* kb = qb + bufElems;
    float* vb = kb + bufElems;

    const int M = BATCH * TSEQ;  // 8192
    dim3 gg(CDIM / 64, M / 64);  // (16, 128)
    dim3 bb(256);

    gemm_bias_kernel<<<gg, bb, 0, stream>>>(x, Wq, bq, qb, M, CDIM, CDIM);
    gemm_bias_kernel<<<gg, bb, 0, stream>>>(x, Wk, bk, kb, M, CDIM, CDIM);
    gemm_bias_kernel<<<gg, bb, 0, stream>>>(x, Wv, bv, vb, M, CDIM, CDIM);

    dim3 ga(TSEQ / 64, NHEADS, BATCH);  // (32, 16, 4)
    attn_kernel<<<ga, bb, 0, stream>>>(qb, kb, vb, qb);

    gemm_bias_kernel<<<gg, bb, 0, stream>>>(qb, Wp, bp, out, M, CDIM, CDIM);
}

// Round 2
// 422.833 us; speedup vs baseline: 5.0240x; 5.0240x over previous
//
#include <hip/hip_runtime.h>
#include <hip/hip_bf16.h>

#define CDIM   1024
#define NHEADS 16
#define DHEAD  64
#define BATCH  4
#define TSEQ   2048
#define MROWS  (BATCH * TSEQ)
#define NEG_BIG (-1e30f)

typedef __attribute__((ext_vector_type(8))) short bf16x8;
typedef __attribute__((ext_vector_type(4))) float f32x4;

__device__ __forceinline__ unsigned short f2bf(float f) {
    __hip_bfloat16 h = __float2bfloat16(f);
    return *reinterpret_cast<unsigned short*>(&h);
}

// ---------------- x: fp32 -> bf16 (8 elems/thread) --------------------------
__global__ __launch_bounds__(256)
void cvt_x_kernel(const float* __restrict__ in, unsigned short* __restrict__ out)
{
    size_t i = (size_t)blockIdx.x * 256 + threadIdx.x;   // one per 8 elems
    const float4* p = reinterpret_cast<const float4*>(in) + i * 2;
    float4 a = p[0], b = p[1];
    uint4 o;
    o.x = (unsigned)f2bf(a.x) | ((unsigned)f2bf(a.y) << 16);
    o.y = (unsigned)f2bf(a.z) | ((unsigned)f2bf(a.w) << 16);
    o.z = (unsigned)f2bf(b.x) | ((unsigned)f2bf(b.y) << 16);
    o.w = (unsigned)f2bf(b.z) | ((unsigned)f2bf(b.w) << 16);
    *reinterpret_cast<uint4*>(out + i * 8) = o;
}

// ---------------- W[K][N] fp32 -> W^T[N][K] bf16 (32x32 LDS tiles) ----------
__global__ __launch_bounds__(256)
void wt_kernel(const float* __restrict__ W0, const float* __restrict__ W1,
               const float* __restrict__ W2, const float* __restrict__ W3,
               unsigned short* __restrict__ T0, unsigned short* __restrict__ T1,
               unsigned short* __restrict__ T2, unsigned short* __restrict__ T3)
{
    const float* W; unsigned short* T;
    switch (blockIdx.z) {
        case 0:  W = W0; T = T0; break;
        case 1:  W = W1; T = T1; break;
        case 2:  W = W2; T = T2; break;
        default: W = W3; T = T3; break;
    }
    __shared__ float tile[32][33];
    const int t = threadIdx.x;
    const int r = t >> 3;          // 0..31
    const int c4 = (t & 7) * 4;    // 0..28
    const int n0 = blockIdx.x * 32, k0 = blockIdx.y * 32;
    float4 v = *reinterpret_cast<const float4*>(&W[(size_t)(k0 + r) * CDIM + n0 + c4]);
    tile[r][c4 + 0] = v.x; tile[r][c4 + 1] = v.y;
    tile[r][c4 + 2] = v.z; tile[r][c4 + 3] = v.w;
    __syncthreads();
    uint2 o;
    o.x = (unsigned)f2bf(tile[c4 + 0][r]) | ((unsigned)f2bf(tile[c4 + 1][r]) << 16);
    o.y = (unsigned)f2bf(tile[c4 + 2][r]) | ((unsigned)f2bf(tile[c4 + 3][r]) << 16);
    *reinterpret_cast<uint2*>(&T[(size_t)(n0 + r) * CDIM + k0 + c4]) = o;
}

// ---------------- bf16 MFMA GEMM: C[M,N] = A[M,K] @ B^T[N,K]^T + bias -------
// 128x128 tile, BK=32, 256 thr = 4 waves (2x2), each wave 64x64 out.
// OUTMODE 0: bf16 out, 1: fp32 out.
template<int OUTMODE>
__global__ __launch_bounds__(256)
void gemm_mfma(const unsigned short* __restrict__ A,
               const unsigned short* __restrict__ BT,
               const float* __restrict__ bias,
               void* __restrict__ Cout, int M, int N, int K)
{
    __shared__ unsigned short As[128][40];   // 80B row stride (16B-aligned)
    __shared__ unsigned short Bs[128][40];
    const int tid  = threadIdx.x;
    const int m0   = blockIdx.y * 128, n0 = blockIdx.x * 128;
    const int lane = tid & 63, wid = tid >> 6;
    const int wr = wid >> 1, wc = wid & 1;
    const int lj = lane & 15, lg = lane >> 4;
    const int srow = tid >> 1, shalf = tid & 1;   // staging: 128 rows x 2 halves

    f32x4 acc[4][4];
    #pragma unroll
    for (int i = 0; i < 4; ++i)
        #pragma unroll
        for (int j = 0; j < 4; ++j) acc[i][j] = f32x4{0.f, 0.f, 0.f, 0.f};

    for (int k0 = 0; k0 < K; k0 += 32) {
        __syncthreads();
        {
            const uint4* ga = reinterpret_cast<const uint4*>(
                A + (size_t)(m0 + srow) * K + k0 + shalf * 16);
            uint4 a0 = ga[0], a1 = ga[1];
            const uint4* gb = reinterpret_cast<const uint4*>(
                BT + (size_t)(n0 + srow) * K + k0 + shalf * 16);
            uint4 b0 = gb[0], b1 = gb[1];
            *reinterpret_cast<uint4*>(&As[srow][shalf * 16 + 0]) = a0;
            *reinterpret_cast<uint4*>(&As[srow][shalf * 16 + 8]) = a1;
            *reinterpret_cast<uint4*>(&Bs[srow][shalf * 16 + 0]) = b0;
            *reinterpret_cast<uint4*>(&Bs[srow][shalf * 16 + 8]) = b1;
        }
        __syncthreads();
        bf16x8 af[4], bf[4];
        #pragma unroll
        for (int i = 0; i < 4; ++i)
            af[i] = *reinterpret_cast<const bf16x8*>(&As[wr * 64 + i * 16 + lj][lg * 8]);
        #pragma unroll
        for (int j = 0; j < 4; ++j)
            bf[j] = *reinterpret_cast<const bf16x8*>(&Bs[wc * 64 + j * 16 + lj][lg * 8]);
        #pragma unroll
        for (int i = 0; i < 4; ++i)
            #pragma unroll
            for (int j = 0; j < 4; ++j)
                acc[i][j] = __builtin_amdgcn_mfma_f32_16x16x32_bf16(af[i], bf[j], acc[i][j], 0, 0, 0);
    }

    float bcol[4];
    #pragma unroll
    for (int j = 0; j < 4; ++j) bcol[j] = bias[n0 + wc * 64 + j * 16 + lj];

    #pragma unroll
    for (int i = 0; i < 4; ++i) {
        #pragma unroll
        for (int r = 0; r < 4; ++r) {
            const int row = m0 + wr * 64 + i * 16 + lg * 4 + r;
            #pragma unroll
            for (int j = 0; j < 4; ++j) {
                const int col = n0 + wc * 64 + j * 16 + lj;
                float v = acc[i][j][r] + bcol[j];
                if (OUTMODE == 0)
                    reinterpret_cast<unsigned short*>(Cout)[(size_t)row * N + col] = f2bf(v);
                else
                    reinterpret_cast<float*>(Cout)[(size_t)row * N + col] = v;
            }
        }
    }
}

// ---------------- MFMA flash attention --------------------------------------
// Block = (qt, h, b): 64 q rows, 4 waves x 16 rows. K-tiles of 64 keys.
__global__ __launch_bounds__(256)
void attn_mfma(const unsigned short* __restrict__ Qb, const unsigned short* __restrict__ Kb,
               const unsigned short* __restrict__ Vb, unsigned short* __restrict__ Yb)
{
    __shared__ unsigned short Ks [64][72];      // [key][d]   144B stride
    __shared__ unsigned short VTs[64][72];      // [d][key]   144B stride
    __shared__ unsigned short Ps [4][16][72];   // per-wave [q][key]

    const int tid = threadIdx.x, lane = tid & 63, wid = tid >> 6;
    const int lj = lane & 15, lg = lane >> 4;
    const int qt = blockIdx.x, h = blockIdx.y, b = blockIdx.z;
    const size_t base = (size_t)b * TSEQ * CDIM + (size_t)h * DHEAD;

    // Q fragments in registers (A-operand: row = lj, k = lg*8 + j + 32*ks)
    bf16x8 qf[2];
    {
        const unsigned short* qp = Qb + base + (size_t)(qt * 64 + wid * 16 + lj) * CDIM + lg * 8;
        qf[0] = *reinterpret_cast<const bf16x8*>(qp);
        qf[1] = *reinterpret_cast<const bf16x8*>(qp + 32);
    }

    f32x4 yacc[4];
    #pragma unroll
    for (int t = 0; t < 4; ++t) yacc[t] = f32x4{0.f, 0.f, 0.f, 0.f};
    float mrow[4] = {NEG_BIG, NEG_BIG, NEG_BIG, NEG_BIG};
    float lrow[4] = {0.f, 0.f, 0.f, 0.f};

    for (int kt = 0; kt <= qt; ++kt) {
        __syncthreads();
        // ---- stage K [key][d]: coalesced 16B reads, min-conflict b128 writes
        #pragma unroll
        for (int it = 0; it < 2; ++it) {
            const int key = (tid >> 3) + it * 32;
            const int d0  = (tid & 7) * 8;
            *reinterpret_cast<uint4*>(&Ks[key][d0]) =
                *reinterpret_cast<const uint4*>(Kb + base + (size_t)(kt * 64 + key) * CDIM + d0);
        }
        // ---- stage V^T [d][key]: key-pairs packed as b32 (conflict-free)
        {
            const int k2 = 2 * (tid & 31);
            const int d0 = (tid >> 5) * 8;
            const unsigned short* va = Vb + base + (size_t)(kt * 64 + k2) * CDIM + d0;
            unsigned short a8[8], b8[8];
            *reinterpret_cast<uint4*>(a8) = *reinterpret_cast<const uint4*>(va);
            *reinterpret_cast<uint4*>(b8) = *reinterpret_cast<const uint4*>(va + CDIM);
            #pragma unroll
            for (int i = 0; i < 8; ++i) {
                unsigned int w = (unsigned)a8[i] | ((unsigned)b8[i] << 16);
                *reinterpret_cast<unsigned int*>(&VTs[d0 + i][k2]) = w;
            }
        }
        __syncthreads();

        // ---- S = Q K^T (8 mfma)
        f32x4 s[4];
        #pragma unroll
        for (int t = 0; t < 4; ++t) s[t] = f32x4{0.f, 0.f, 0.f, 0.f};
        #pragma unroll
        for (int ks = 0; ks < 2; ++ks)
            #pragma unroll
            for (int t = 0; t < 4; ++t) {
                bf16x8 kf = *reinterpret_cast<const bf16x8*>(&Ks[t * 16 + lj][ks * 32 + lg * 8]);
                s[t] = __builtin_amdgcn_mfma_f32_16x16x32_bf16(qf[ks], kf, s[t], 0, 0, 0);
            }

        // ---- scale + causal mask
        float sv[4][4];
        #pragma unroll
        for (int t = 0; t < 4; ++t)
            #pragma unroll
            for (int r = 0; r < 4; ++r) {
                float x = s[t][r] * 0.125f;
                if (kt == qt) {
                    if (t * 16 + lj > wid * 16 + lg * 4 + r) x = NEG_BIG;
                }
                sv[t][r] = x;
            }

        // ---- wave-parallel online softmax (rows live in 16-lane groups)
        float alpha[4], ps[4][4];
        #pragma unroll
        for (int r = 0; r < 4; ++r) {
            float m2 = fmaxf(fmaxf(sv[0][r], sv[1][r]), fmaxf(sv[2][r], sv[3][r]));
            m2 = fmaxf(m2, __shfl_xor(m2, 1));
            m2 = fmaxf(m2, __shfl_xor(m2, 2));
            m2 = fmaxf(m2, __shfl_xor(m2, 4));
            m2 = fmaxf(m2, __shfl_xor(m2, 8));
            float mnew = fmaxf(mrow[r], m2);
            alpha[r] = __expf(mrow[r] - mnew);
            mrow[r] = mnew;
        }
        #pragma unroll
        for (int r = 0; r < 4; ++r) {
            float s0 = 0.f;
            #pragma unroll
            for (int t = 0; t < 4; ++t) {
                float p = __expf(sv[t][r] - mrow[r]);
                ps[t][r] = p;
                s0 += p;
            }
            s0 += __shfl_xor(s0, 1);
            s0 += __shfl_xor(s0, 2);
            s0 += __shfl_xor(s0, 4);
            s0 += __shfl_xor(s0, 8);
            lrow[r] = lrow[r] * alpha[r] + s0;
        }
        #pragma unroll
        for (int t = 0; t < 4; ++t)
            #pragma unroll
            for (int r = 0; r < 4; ++r) yacc[t][r] *= alpha[r];

        // ---- P -> bf16 -> per-wave LDS (pair-packed b32, even lanes)
        #pragma unroll
        for (int t = 0; t < 4; ++t)
            #pragma unroll
            for (int r = 0; r < 4; ++r) {
                unsigned int own = f2bf(ps[t][r]);
                unsigned int other = (unsigned int)__shfl_xor((int)own, 1);
                if ((lj & 1) == 0) {
                    unsigned int w = (own & 0xffffu) | (other << 16);
                    *reinterpret_cast<unsigned int*>(&Ps[wid][lg * 4 + r][t * 16 + lj]) = w;
                }
            }

        // ---- Y += P @ V (8 mfma); same-wave LDS ops are in-order, no barrier
        bf16x8 pa[2];
        #pragma unroll
        for (int ks = 0; ks < 2; ++ks)
            pa[ks] = *reinterpret_cast<const bf16x8*>(&Ps[wid][lj][ks * 32 + lg * 8]);
        #pragma unroll
        for (int t = 0; t < 4; ++t)
            #pragma unroll
            for (int ks = 0; ks < 2; ++ks) {
                bf16x8 vf = *reinterpret_cast<const bf16x8*>(&VTs[t * 16 + lj][ks * 32 + lg * 8]);
                yacc[t] = __builtin_amdgcn_mfma_f32_16x16x32_bf16(pa[ks], vf, yacc[t], 0, 0, 0);
            }
    }

    // ---- epilogue: normalize, store bf16
    #pragma unroll
    for (int r = 0; r < 4; ++r) {
        float inv = 1.f / lrow[r];
        const size_t rb = base + (size_t)(qt * 64 + wid * 16 + lg * 4 + r) * CDIM;
        #pragma unroll
        for (int t = 0; t < 4; ++t)
            Yb[rb + t * 16 + lj] = f2bf(yacc[t][r] * inv);
    }
}

// ---------------------------------------------------------------------------
extern "C" void kernel_launch(void* const* d_in, const int* in_sizes, int n_in,
                              void* d_out, int out_size, void* d_ws, size_t ws_size,
                              hipStream_t stream)
{
    const float* x  = (const float*)d_in[0];
    const float* Wk = (const float*)d_in[1];
    const float* bk = (const float*)d_in[2];
    const float* Wq = (const float*)d_in[3];
    const float* bq = (const float*)d_in[4];
    const float* Wv = (const float*)d_in[5];
    const float* bv = (const float*)d_in[6];
    const float* Wp = (const float*)d_in[7];
    const float* bp = (const float*)d_in[8];

    const size_t xe = (size_t)MROWS * CDIM;   // 8,388,608
    const size_t we = (size_t)CDIM * CDIM;    // 1,048,576
    unsigned short* xb  = (unsigned short*)d_ws;
    unsigned short* wqt = xb  + xe;
    unsigned short* wkt = wqt + we;
    unsigned short* wvt = wkt + we;
    unsigned short* wpt = wvt + we;
    unsigned short* qb  = wpt + we;
    unsigned short* kb  = qb  + xe;
    unsigned short* vb  = kb  + xe;
    unsigned short* ab  = vb  + xe;

    cvt_x_kernel<<<(int)(xe / 8 / 256), 256, 0, stream>>>(x, xb);
    wt_kernel<<<dim3(32, 32, 4), 256, 0, stream>>>(Wq, Wk, Wv, Wp, wqt, wkt, wvt, wpt);

    dim3 gg(CDIM / 128, MROWS / 128);   // (8, 64)
    gemm_mfma<0><<<gg, 256, 0, stream>>>(xb, wqt, bq, qb, MROWS, CDIM, CDIM);
    gemm_mfma<0><<<gg, 256, 0, stream>>>(xb, wkt, bk, kb, MROWS, CDIM, CDIM);
    gemm_mfma<0><<<gg, 256, 0, stream>>>(xb, wvt, bv, vb, MROWS, CDIM, CDIM);

    attn_mfma<<<dim3(TSEQ / 64, NHEADS, BATCH), 256, 0, stream>>>(qb, kb, vb, ab);

    gemm_mfma<1><<<gg, 256, 0, stream>>>(ab, wpt, bp, d_out, MROWS, CDIM, CDIM);
}

// Round 3
// 264.250 us; speedup vs baseline: 8.0390x; 1.6001x over previous
//
#include <hip/hip_runtime.h>
#include <hip/hip_bf16.h>

#define CDIM   1024
#define NHEADS 16
#define DHEAD  64
#define BATCH  4
#define TSEQ   2048
#define MROWS  (BATCH * TSEQ)
#define NEG_BIG (-1e30f)
#define MASKVAL (-3.0e38f)
#define SCALE_L2E 0.18033688011f   /* 0.125 * log2(e) */
#define DEFER_TH 11.5416f          /* 8 nats in log2 units */

typedef __attribute__((ext_vector_type(8)))  short bf16x8;
typedef __attribute__((ext_vector_type(4)))  float f32x4;
typedef __attribute__((ext_vector_type(16))) float f32x16;

__device__ __forceinline__ unsigned short f2bf(float f) {
    __hip_bfloat16 h = __float2bfloat16(f);
    return *reinterpret_cast<unsigned short*>(&h);
}
__device__ __forceinline__ unsigned int pk2(float a, float b) {
    return (unsigned)f2bf(a) | ((unsigned)f2bf(b) << 16);
}

// ---------------- x: fp32 -> bf16 (8 elems/thread) --------------------------
__global__ __launch_bounds__(256)
void cvt_x_kernel(const float* __restrict__ in, unsigned short* __restrict__ out)
{
    size_t i = (size_t)blockIdx.x * 256 + threadIdx.x;   // one per 8 elems
    const float4* p = reinterpret_cast<const float4*>(in) + i * 2;
    float4 a = p[0], b = p[1];
    uint4 o;
    o.x = (unsigned)f2bf(a.x) | ((unsigned)f2bf(a.y) << 16);
    o.y = (unsigned)f2bf(a.z) | ((unsigned)f2bf(a.w) << 16);
    o.z = (unsigned)f2bf(b.x) | ((unsigned)f2bf(b.y) << 16);
    o.w = (unsigned)f2bf(b.z) | ((unsigned)f2bf(b.w) << 16);
    *reinterpret_cast<uint4*>(out + i * 8) = o;
}

// ---------------- W[K][N] fp32 -> W^T[N][K] bf16 (32x32 LDS tiles) ----------
__global__ __launch_bounds__(256)
void wt_kernel(const float* __restrict__ W0, const float* __restrict__ W1,
               const float* __restrict__ W2, const float* __restrict__ W3,
               unsigned short* __restrict__ T0, unsigned short* __restrict__ T1,
               unsigned short* __restrict__ T2, unsigned short* __restrict__ T3)
{
    const float* W; unsigned short* T;
    switch (blockIdx.z) {
        case 0:  W = W0; T = T0; break;
        case 1:  W = W1; T = T1; break;
        case 2:  W = W2; T = T2; break;
        default: W = W3; T = T3; break;
    }
    __shared__ float tile[32][33];
    const int t = threadIdx.x;
    const int r = t >> 3;          // 0..31
    const int c4 = (t & 7) * 4;    // 0..28
    const int n0 = blockIdx.x * 32, k0 = blockIdx.y * 32;
    float4 v = *reinterpret_cast<const float4*>(&W[(size_t)(k0 + r) * CDIM + n0 + c4]);
    tile[r][c4 + 0] = v.x; tile[r][c4 + 1] = v.y;
    tile[r][c4 + 2] = v.z; tile[r][c4 + 3] = v.w;
    __syncthreads();
    uint2 o;
    o.x = (unsigned)f2bf(tile[c4 + 0][r]) | ((unsigned)f2bf(tile[c4 + 1][r]) << 16);
    o.y = (unsigned)f2bf(tile[c4 + 2][r]) | ((unsigned)f2bf(tile[c4 + 3][r]) << 16);
    *reinterpret_cast<uint2*>(&T[(size_t)(n0 + r) * CDIM + k0 + c4]) = o;
}

// ---------------- bf16 MFMA GEMM: C[M,N] = A[M,K] @ B^T[N,K]^T + bias -------
// 128x128 tile, BK=32, 256 thr = 4 waves (2x2), each wave 64x64 out.
template<int OUTMODE>
__global__ __launch_bounds__(256)
void gemm_mfma(const unsigned short* __restrict__ A,
               const unsigned short* __restrict__ BT,
               const float* __restrict__ bias,
               void* __restrict__ Cout, int M, int N, int K)
{
    __shared__ unsigned short As[128][40];   // 80B row stride (16B-aligned)
    __shared__ unsigned short Bs[128][40];
    const int tid  = threadIdx.x;
    const int m0   = blockIdx.y * 128, n0 = blockIdx.x * 128;
    const int lane = tid & 63, wid = tid >> 6;
    const int wr = wid >> 1, wc = wid & 1;
    const int lj = lane & 15, lg = lane >> 4;
    const int srow = tid >> 1, shalf = tid & 1;

    f32x4 acc[4][4];
    #pragma unroll
    for (int i = 0; i < 4; ++i)
        #pragma unroll
        for (int j = 0; j < 4; ++j) acc[i][j] = f32x4{0.f, 0.f, 0.f, 0.f};

    for (int k0 = 0; k0 < K; k0 += 32) {
        __syncthreads();
        {
            const uint4* ga = reinterpret_cast<const uint4*>(
                A + (size_t)(m0 + srow) * K + k0 + shalf * 16);
            uint4 a0 = ga[0], a1 = ga[1];
            const uint4* gb = reinterpret_cast<const uint4*>(
                BT + (size_t)(n0 + srow) * K + k0 + shalf * 16);
            uint4 b0 = gb[0], b1 = gb[1];
            *reinterpret_cast<uint4*>(&As[srow][shalf * 16 + 0]) = a0;
            *reinterpret_cast<uint4*>(&As[srow][shalf * 16 + 8]) = a1;
            *reinterpret_cast<uint4*>(&Bs[srow][shalf * 16 + 0]) = b0;
            *reinterpret_cast<uint4*>(&Bs[srow][shalf * 16 + 8]) = b1;
        }
        __syncthreads();
        bf16x8 af[4], bfr[4];
        #pragma unroll
        for (int i = 0; i < 4; ++i)
            af[i] = *reinterpret_cast<const bf16x8*>(&As[wr * 64 + i * 16 + lj][lg * 8]);
        #pragma unroll
        for (int j = 0; j < 4; ++j)
            bfr[j] = *reinterpret_cast<const bf16x8*>(&Bs[wc * 64 + j * 16 + lj][lg * 8]);
        #pragma unroll
        for (int i = 0; i < 4; ++i)
            #pragma unroll
            for (int j = 0; j < 4; ++j)
                acc[i][j] = __builtin_amdgcn_mfma_f32_16x16x32_bf16(af[i], bfr[j], acc[i][j], 0, 0, 0);
    }

    float bcol[4];
    #pragma unroll
    for (int j = 0; j < 4; ++j) bcol[j] = bias[n0 + wc * 64 + j * 16 + lj];

    #pragma unroll
    for (int i = 0; i < 4; ++i) {
        #pragma unroll
        for (int r = 0; r < 4; ++r) {
            const int row = m0 + wr * 64 + i * 16 + lg * 4 + r;
            #pragma unroll
            for (int j = 0; j < 4; ++j) {
                const int col = n0 + wc * 64 + j * 16 + lj;
                float v = acc[i][j][r] + bcol[j];
                if (OUTMODE == 0)
                    reinterpret_cast<unsigned short*>(Cout)[(size_t)row * N + col] = f2bf(v);
                else
                    reinterpret_cast<float*>(Cout)[(size_t)row * N + col] = v;
            }
        }
    }
}

// ---------------- MFMA flash attention, swapped-QK 32x32 structure ----------
// Block: 256 thr = 4 waves, each wave 32 q-rows -> 128-row q-tile.
// Block processes q-tile pair (qi, 15-qi) sequentially -> uniform load.
// S^T = mfma(K, Q^T): lane holds P-row slice for q = lane&31 (in-reg softmax).
// Y^T = mfma(V^T, P^T): softmax stats stay lane-local (col = q).
// K/V LDS XOR-swizzled (byte ^= (row&7)<<4): bank-minimal b128 reads.
#define PV_STEP(m, T, rb) { \
    unsigned int w01 = pk2(T[(rb)+0], T[(rb)+1]); \
    unsigned int w23 = pk2(T[(rb)+2], T[(rb)+3]); \
    unsigned int w45 = pk2(T[(rb)+4], T[(rb)+5]); \
    unsigned int w67 = pk2(T[(rb)+6], T[(rb)+7]); \
    asm("v_permlane32_swap_b32 %0, %1" : "+v"(w01), "+v"(w45)); \
    asm("v_permlane32_swap_b32 %0, %1" : "+v"(w23), "+v"(w67)); \
    union { unsigned int u[4]; bf16x8 v; } pa; \
    pa.u[0] = w01; pa.u[1] = w23; pa.u[2] = w45; pa.u[3] = w67; \
    const int voff = (32 * (m) + 16 * hi) ^ ((lq & 7) << 4); \
    bf16x8 va = *reinterpret_cast<const bf16x8*>(VTB + lq * 128 + voff); \
    bf16x8 vb = *reinterpret_cast<const bf16x8*>(VTB + (lq + 32) * 128 + voff); \
    y0 = __builtin_amdgcn_mfma_f32_32x32x16_bf16(va, pa.v, y0, 0, 0, 0); \
    y1 = __builtin_amdgcn_mfma_f32_32x32x16_bf16(vb, pa.v, y1, 0, 0, 0); \
}

__global__ __launch_bounds__(256)
void attn_mfma2(const unsigned short* __restrict__ Qb, const unsigned short* __restrict__ Kb,
                const unsigned short* __restrict__ Vb, unsigned short* __restrict__ Yb)
{
    __shared__ unsigned short Ks[64 * 64];    // [key][d], swizzled
    __shared__ unsigned short VTs[64 * 64];   // [d][key], swizzled
    __shared__ unsigned short Ysc[4][32 * 72];// per-wave [q][d], 144B stride

    const int tid = threadIdx.x, lane = tid & 63, wid = tid >> 6;
    const int lq = lane & 31, hi = lane >> 5;
    const int qi = blockIdx.x, h = blockIdx.y, b = blockIdx.z;
    const size_t rowbase = (size_t)b * TSEQ;
    const int hb = h * DHEAD;
    char* KsB = (char*)Ks;
    char* VTB = (char*)VTs;

    for (int iter = 0; iter < 2; ++iter) {
        const int qtile = iter ? (15 - qi) : qi;
        const int q0 = qtile * 128;
        const int wq = q0 + wid * 32;            // wave q base (in-sequence)

        bf16x8 qf[4];                            // Q^T B-frags: d = 16s + 8hi + j
        {
            const unsigned short* qp = Qb + (rowbase + wq + lq) * CDIM + hb + hi * 8;
            #pragma unroll
            for (int s = 0; s < 4; ++s)
                qf[s] = *reinterpret_cast<const bf16x8*>(qp + s * 16);
        }
        f32x16 y0, y1;                           // Y^T tiles: d 0..31 / 32..63
        #pragma unroll
        for (int r = 0; r < 16; ++r) { y0[r] = 0.f; y1[r] = 0.f; }
        float mrow = NEG_BIG, lrow = 0.f;

        const int ktend = 2 * qtile + 2;
        for (int kt = 0; kt < ktend; ++kt) {
            __syncthreads();
            { // stage K [key][d] with XOR swizzle (16B granules)
                const int c = tid & 7;
                #pragma unroll
                for (int p = 0; p < 2; ++p) {
                    const int row = (tid >> 3) + 32 * p;
                    uint4 v = *reinterpret_cast<const uint4*>(
                        Kb + (rowbase + kt * 64 + row) * CDIM + hb + c * 8);
                    *reinterpret_cast<uint4*>(KsB + row * 128 + ((c * 16) ^ ((row & 7) << 4))) = v;
                }
            }
            { // stage V^T [d][key]: key-pairs packed as u32, swizzled
                const int k2 = 2 * (tid & 31), dg = (tid >> 5) * 8;
                const unsigned short* va = Vb + (rowbase + kt * 64 + k2) * CDIM + hb + dg;
                unsigned short a8[8], b8[8];
                *reinterpret_cast<uint4*>(a8) = *reinterpret_cast<const uint4*>(va);
                *reinterpret_cast<uint4*>(b8) = *reinterpret_cast<const uint4*>(va + CDIM);
                #pragma unroll
                for (int i2 = 0; i2 < 8; ++i2) {
                    unsigned int w = (unsigned)a8[i2] | ((unsigned)b8[i2] << 16);
                    const int d = dg + i2;
                    *reinterpret_cast<unsigned int*>(VTB + d * 128 + ((k2 * 2) ^ ((d & 7) << 4))) = w;
                }
            }
            __syncthreads();
            if (kt * 64 > wq + 31) continue;     // tile fully above diagonal for this wave

            // ---- S^T = K Q^T (8 mfma 32x32x16)
            f32x16 s0, s1;
            #pragma unroll
            for (int r = 0; r < 16; ++r) { s0[r] = 0.f; s1[r] = 0.f; }
            #pragma unroll
            for (int s = 0; s < 4; ++s) {
                const int off = (s * 32 + hi * 16) ^ ((lq & 7) << 4);
                bf16x8 k0 = *reinterpret_cast<const bf16x8*>(KsB + lq * 128 + off);
                bf16x8 k1 = *reinterpret_cast<const bf16x8*>(KsB + (lq + 32) * 128 + off);
                s0 = __builtin_amdgcn_mfma_f32_32x32x16_bf16(k0, qf[s], s0, 0, 0, 0);
                s1 = __builtin_amdgcn_mfma_f32_32x32x16_bf16(k1, qf[s], s1, 0, 0, 0);
            }

            // ---- scale (log2e-folded) + causal mask
            const bool diag = (kt * 64 + 63) > wq;
            const int q_own = wq + lq;
            #pragma unroll
            for (int r = 0; r < 16; ++r) {
                float v0 = s0[r] * SCALE_L2E;
                float v1 = s1[r] * SCALE_L2E;
                if (diag) {
                    const int kl = kt * 64 + (r & 3) + 8 * (r >> 2) + 4 * hi;
                    if (kl > q_own) v0 = MASKVAL;
                    if (kl + 32 > q_own) v1 = MASKVAL;
                }
                s0[r] = v0; s1[r] = v1;
            }

            // ---- in-register row max (31 ops) + pair exchange
            float pm = MASKVAL;
            #pragma unroll
            for (int r = 0; r < 16; ++r) pm = fmaxf(pm, fmaxf(s0[r], s1[r]));
            pm = fmaxf(pm, __shfl_xor(pm, 32));

            // ---- defer-max rescale (T13)
            if (__any(pm > mrow + DEFER_TH)) {
                const float mnew = fmaxf(mrow, pm);
                const float alpha = exp2f(mrow - mnew);
                #pragma unroll
                for (int r = 0; r < 16; ++r) { y0[r] *= alpha; y1[r] *= alpha; }
                lrow *= alpha;
                mrow = mnew;
            }
            // ---- exp2 + in-register row sum
            float sum = 0.f;
            #pragma unroll
            for (int r = 0; r < 16; ++r) {
                s0[r] = exp2f(s0[r] - mrow); sum += s0[r];
                s1[r] = exp2f(s1[r] - mrow); sum += s1[r];
            }
            sum += __shfl_xor(sum, 32);
            lrow += sum;

            // ---- Y^T += V^T P^T (8 mfma); P^T frags via pack+permlane32_swap
            PV_STEP(0, s0, 0)
            PV_STEP(1, s0, 8)
            PV_STEP(2, s1, 0)
            PV_STEP(3, s1, 8)
        }

        // ---- epilogue: normalize, transpose via per-wave LDS, coalesced store
        {
            const float inv = 1.f / lrow;
            char* ysb = (char*)&Ysc[wid][0];
            #pragma unroll
            for (int t = 0; t < 8; ++t) {
                const int dl = ((2 * t) & 3) + 8 * (t >> 1) + 4 * hi;
                unsigned int wa = pk2(y0[2 * t] * inv, y0[2 * t + 1] * inv);
                unsigned int wb = pk2(y1[2 * t] * inv, y1[2 * t + 1] * inv);
                *reinterpret_cast<unsigned int*>(ysb + lq * 144 + dl * 2) = wa;
                *reinterpret_cast<unsigned int*>(ysb + lq * 144 + (dl + 32) * 2) = wb;
            }
            // same-wave LDS ordering: compiler inserts lgkmcnt wait
            #pragma unroll
            for (int u = 0; u < 4; ++u) {
                const int rr = lane >> 1, ch = (lane & 1) + 2 * u;
                uint4 val = *reinterpret_cast<const uint4*>(ysb + rr * 144 + ch * 16);
                *reinterpret_cast<uint4*>(Yb + (rowbase + q0 + wid * 32 + rr) * CDIM + hb + ch * 8) = val;
            }
        }
    }
}

// ---------------------------------------------------------------------------
extern "C" void kernel_launch(void* const* d_in, const int* in_sizes, int n_in,
                              void* d_out, int out_size, void* d_ws, size_t ws_size,
                              hipStream_t stream)
{
    const float* x  = (const float*)d_in[0];
    const float* Wk = (const float*)d_in[1];
    const float* bk = (const float*)d_in[2];
    const float* Wq = (const float*)d_in[3];
    const float* bq = (const float*)d_in[4];
    const float* Wv = (const float*)d_in[5];
    const float* bv = (const float*)d_in[6];
    const float* Wp = (const float*)d_in[7];
    const float* bp = (const float*)d_in[8];

    const size_t xe = (size_t)MROWS * CDIM;   // 8,388,608
    const size_t we = (size_t)CDIM * CDIM;    // 1,048,576
    unsigned short* xb  = (unsigned short*)d_ws;
    unsigned short* wqt = xb  + xe;
    unsigned short* wkt = wqt + we;
    unsigned short* wvt = wkt + we;
    unsigned short* wpt = wvt + we;
    unsigned short* qb  = wpt + we;
    unsigned short* kb  = qb  + xe;
    unsigned short* vb  = kb  + xe;
    unsigned short* ab  = vb  + xe;

    cvt_x_kernel<<<(int)(xe / 8 / 256), 256, 0, stream>>>(x, xb);
    wt_kernel<<<dim3(32, 32, 4), 256, 0, stream>>>(Wq, Wk, Wv, Wp, wqt, wkt, wvt, wpt);

    dim3 gg(CDIM / 128, MROWS / 128);   // (8, 64)
    gemm_mfma<0><<<gg, 256, 0, stream>>>(xb, wqt, bq, qb, MROWS, CDIM, CDIM);
    gemm_mfma<0><<<gg, 256, 0, stream>>>(xb, wkt, bk, kb, MROWS, CDIM, CDIM);
    gemm_mfma<0><<<gg, 256, 0, stream>>>(xb, wvt, bv, vb, MROWS, CDIM, CDIM);

    attn_mfma2<<<dim3(8, NHEADS, BATCH), 256, 0, stream>>>(qb, kb, vb, ab);

    gemm_mfma<1><<<gg, 256, 0, stream>>>(ab, wpt, bp, d_out, MROWS, CDIM, CDIM);
}

// Round 4
// 249.993 us; speedup vs baseline: 8.4975x; 1.0570x over previous
//
#include <hip/hip_runtime.h>
#include <hip/hip_bf16.h>

#define CDIM   1024
#define NHEADS 16
#define DHEAD  64
#define BATCH  4
#define TSEQ   2048
#define MROWS  (BATCH * TSEQ)
#define QSTR   3072                /* fused qkv row stride */
#define NEG_BIG (-1e30f)
#define MASKVAL (-3.0e38f)
#define SCALE_L2E 0.18033688011f   /* 0.125 * log2(e) */
#define DEFER_TH 11.5416f          /* 8 nats in log2 units */

typedef __attribute__((ext_vector_type(8)))  short bf16x8;
typedef __attribute__((ext_vector_type(4)))  float f32x4;
typedef __attribute__((ext_vector_type(16))) float f32x16;

__device__ __forceinline__ unsigned short f2bf(float f) {
    __hip_bfloat16 h = __float2bfloat16(f);
    return *reinterpret_cast<unsigned short*>(&h);
}
__device__ __forceinline__ unsigned int pk2(float a, float b) {
    return (unsigned)f2bf(a) | ((unsigned)f2bf(b) << 16);
}

// ---------------- x: fp32 -> bf16 (8 elems/thread) --------------------------
__global__ __launch_bounds__(256)
void cvt_x_kernel(const float* __restrict__ in, unsigned short* __restrict__ out)
{
    size_t i = (size_t)blockIdx.x * 256 + threadIdx.x;
    const float4* p = reinterpret_cast<const float4*>(in) + i * 2;
    float4 a = p[0], b = p[1];
    uint4 o;
    o.x = (unsigned)f2bf(a.x) | ((unsigned)f2bf(a.y) << 16);
    o.y = (unsigned)f2bf(a.z) | ((unsigned)f2bf(a.w) << 16);
    o.z = (unsigned)f2bf(b.x) | ((unsigned)f2bf(b.y) << 16);
    o.w = (unsigned)f2bf(b.z) | ((unsigned)f2bf(b.w) << 16);
    *reinterpret_cast<uint4*>(out + i * 8) = o;
}

// ---------------- W[K][N] fp32 -> W^T[N][K] bf16 (32x32 LDS tiles) ----------
__global__ __launch_bounds__(256)
void wt_kernel(const float* __restrict__ W0, const float* __restrict__ W1,
               const float* __restrict__ W2, const float* __restrict__ W3,
               unsigned short* __restrict__ T0, unsigned short* __restrict__ T1,
               unsigned short* __restrict__ T2, unsigned short* __restrict__ T3)
{
    const float* W; unsigned short* T;
    switch (blockIdx.z) {
        case 0:  W = W0; T = T0; break;
        case 1:  W = W1; T = T1; break;
        case 2:  W = W2; T = T2; break;
        default: W = W3; T = T3; break;
    }
    __shared__ float tile[32][33];
    const int t = threadIdx.x;
    const int r = t >> 3;
    const int c4 = (t & 7) * 4;
    const int n0 = blockIdx.x * 32, k0 = blockIdx.y * 32;
    float4 v = *reinterpret_cast<const float4*>(&W[(size_t)(k0 + r) * CDIM + n0 + c4]);
    tile[r][c4 + 0] = v.x; tile[r][c4 + 1] = v.y;
    tile[r][c4 + 2] = v.z; tile[r][c4 + 3] = v.w;
    __syncthreads();
    uint2 o;
    o.x = (unsigned)f2bf(tile[c4 + 0][r]) | ((unsigned)f2bf(tile[c4 + 1][r]) << 16);
    o.y = (unsigned)f2bf(tile[c4 + 2][r]) | ((unsigned)f2bf(tile[c4 + 3][r]) << 16);
    *reinterpret_cast<uint2*>(&T[(size_t)(n0 + r) * CDIM + k0 + c4]) = o;
}

// ---------------- bias concat [bq|bk|bv] ------------------------------------
__global__ __launch_bounds__(256)
void pack_bias(const float* __restrict__ bq, const float* __restrict__ bk,
               const float* __restrict__ bv, float* __restrict__ o)
{
    int i = blockIdx.x * 256 + threadIdx.x;   // 0..3071
    float v = (i < 1024) ? bq[i] : (i < 2048 ? bk[i - 1024] : bv[i - 2048]);
    o[i] = v;
}

// ---------------- m97-structure GEMM: C = A @ BT^T + bias, glds staging -----
// 128x128 tile, BK=32, 4 waves (2x2). LDS linear rows of 64B, 4 granules of
// 16B; physical slot s holds logical granule s^(r&3) (inverse-swizzled global
// source + swizzled read => bank-minimal 8 words/bank on ds_read_b128).
// Cols < nScaled get *SCALE_L2E in epilogue (folds softmax scale into Q).
template<int OUTMODE>
__global__ __launch_bounds__(256)
void gemm_glds(const unsigned short* __restrict__ A,
               const unsigned short* __restrict__ BT,
               const float* __restrict__ bias,
               void* __restrict__ Cout, int M, int N, int K, int nScaled)
{
    __shared__ __align__(16) unsigned short As[128 * 32];
    __shared__ __align__(16) unsigned short Bs[128 * 32];
    const int tid = threadIdx.x;
    const int nbn = N >> 7;
    const int bid = blockIdx.x;
    const int wg  = (bid & 7) * ((int)gridDim.x >> 3) + (bid >> 3);  // XCD swizzle
    const int n0  = (wg % nbn) * 128;
    const int m0  = (wg / nbn) * 128;

    const int lane = tid & 63, w = tid >> 6;
    const int wr = w >> 1, wc = w & 1;
    const int lj = lane & 15, lg = lane >> 4;
    const int rl = lane >> 2, sl = lane & 3;

    char* AsB = (char*)As;
    char* BsB = (char*)Bs;

    f32x4 acc[4][4];
    #pragma unroll
    for (int i = 0; i < 4; ++i)
        #pragma unroll
        for (int j = 0; j < 4; ++j) acc[i][j] = f32x4{0.f, 0.f, 0.f, 0.f};

    for (int k0 = 0; k0 < K; k0 += 32) {
        __syncthreads();
        #pragma unroll
        for (int t = 0; t < 2; ++t) {
            const int r = t * 64 + w * 16 + rl;
            const int g = sl ^ (r & 3);
            __builtin_amdgcn_global_load_lds(
                (const __attribute__((address_space(1))) void*)(A + (size_t)(m0 + r) * K + k0 + 8 * g),
                (__attribute__((address_space(3))) void*)(AsB + t * 4096 + w * 1024),
                16, 0, 0);
            __builtin_amdgcn_global_load_lds(
                (const __attribute__((address_space(1))) void*)(BT + (size_t)(n0 + r) * K + k0 + 8 * g),
                (__attribute__((address_space(3))) void*)(BsB + t * 4096 + w * 1024),
                16, 0, 0);
        }
        __syncthreads();
        bf16x8 af[4], bfr[4];
        #pragma unroll
        for (int i = 0; i < 4; ++i) {
            const int r = wr * 64 + i * 16 + lj;
            af[i] = *reinterpret_cast<const bf16x8*>(AsB + r * 64 + ((lg ^ (r & 3)) * 16));
        }
        #pragma unroll
        for (int j = 0; j < 4; ++j) {
            const int r = wc * 64 + j * 16 + lj;
            bfr[j] = *reinterpret_cast<const bf16x8*>(BsB + r * 64 + ((lg ^ (r & 3)) * 16));
        }
        #pragma unroll
        for (int i = 0; i < 4; ++i)
            #pragma unroll
            for (int j = 0; j < 4; ++j)
                acc[i][j] = __builtin_amdgcn_mfma_f32_16x16x32_bf16(af[i], bfr[j], acc[i][j], 0, 0, 0);
    }

    const float sc = (n0 < nScaled) ? SCALE_L2E : 1.0f;
    float bcol[4];
    #pragma unroll
    for (int j = 0; j < 4; ++j) bcol[j] = bias[n0 + wc * 64 + j * 16 + lj];

    #pragma unroll
    for (int i = 0; i < 4; ++i) {
        #pragma unroll
        for (int r4 = 0; r4 < 4; ++r4) {
            const int row = m0 + wr * 64 + i * 16 + lg * 4 + r4;
            #pragma unroll
            for (int j = 0; j < 4; ++j) {
                const int col = n0 + wc * 64 + j * 16 + lj;
                float v = (acc[i][j][r4] + bcol[j]) * sc;
                if (OUTMODE == 0)
                    reinterpret_cast<unsigned short*>(Cout)[(size_t)row * N + col] = f2bf(v);
                else
                    reinterpret_cast<float*>(Cout)[(size_t)row * N + col] = v;
            }
        }
    }
}

// ---------------- MFMA flash attention, swapped-QK 32x32 structure ----------
// One 128-row q-tile per block, 4 waves x 32 q-rows. Q pre-scaled by
// 0.125*log2e in GEMM epilogue. qtile mapping balances per-CU work under
// round-robin dispatch: {bx, 15-bx, bx+8, 7-bx} across batch-z.
#define PV_STEP(m, T, rb) { \
    unsigned int w01 = pk2(T[(rb)+0], T[(rb)+1]); \
    unsigned int w23 = pk2(T[(rb)+2], T[(rb)+3]); \
    unsigned int w45 = pk2(T[(rb)+4], T[(rb)+5]); \
    unsigned int w67 = pk2(T[(rb)+6], T[(rb)+7]); \
    asm("v_permlane32_swap_b32 %0, %1" : "+v"(w01), "+v"(w45)); \
    asm("v_permlane32_swap_b32 %0, %1" : "+v"(w23), "+v"(w67)); \
    union { unsigned int u[4]; bf16x8 v; } pa; \
    pa.u[0] = w01; pa.u[1] = w23; pa.u[2] = w45; pa.u[3] = w67; \
    const int voff = (32 * (m) + 16 * hi) ^ ((lq & 7) << 4); \
    bf16x8 va = *reinterpret_cast<const bf16x8*>(VTB + lq * 128 + voff); \
    bf16x8 vb = *reinterpret_cast<const bf16x8*>(VTB + (lq + 32) * 128 + voff); \
    y0 = __builtin_amdgcn_mfma_f32_32x32x16_bf16(va, pa.v, y0, 0, 0, 0); \
    y1 = __builtin_amdgcn_mfma_f32_32x32x16_bf16(vb, pa.v, y1, 0, 0, 0); \
}

__global__ __launch_bounds__(256)
void attn_mfma3(const unsigned short* __restrict__ QKV, unsigned short* __restrict__ Yb)
{
    __shared__ unsigned short Ks[64 * 64];    // [key][d], swizzled
    __shared__ unsigned short VTs[64 * 64];   // [d][key], swizzled
    __shared__ unsigned short Ysc[4][32 * 72];// per-wave [q][d], 144B stride

    const int tid = threadIdx.x, lane = tid & 63, wid = tid >> 6;
    const int lq = lane & 31, hi = lane >> 5;
    const int bx = blockIdx.x, h = blockIdx.y, bz = blockIdx.z;
    const int t0 = (bx + ((bz >> 1) << 3)) & 15;
    const int qtile = (bz & 1) ? (15 - t0) : t0;
    const size_t rowbase = (size_t)bz * TSEQ;
    const int hq = h * DHEAD, hk = 1024 + h * DHEAD, hv = 2048 + h * DHEAD;
    char* KsB = (char*)Ks;
    char* VTB = (char*)VTs;

    const int q0 = qtile * 128;
    const int wq = q0 + wid * 32;

    bf16x8 qf[4];                            // Q^T B-frags: d = 16s + 8hi + j
    {
        const unsigned short* qp = QKV + (rowbase + wq + lq) * QSTR + hq + hi * 8;
        #pragma unroll
        for (int s = 0; s < 4; ++s)
            qf[s] = *reinterpret_cast<const bf16x8*>(qp + s * 16);
    }
    f32x16 y0, y1;                           // Y^T tiles: d 0..31 / 32..63
    #pragma unroll
    for (int r = 0; r < 16; ++r) { y0[r] = 0.f; y1[r] = 0.f; }
    float mrow = NEG_BIG, lrow = 0.f;

    const int ktend = 2 * qtile + 2;
    for (int kt = 0; kt < ktend; ++kt) {
        __syncthreads();
        { // stage K [key][d] with XOR swizzle (16B granules)
            const int c = tid & 7;
            #pragma unroll
            for (int p = 0; p < 2; ++p) {
                const int row = (tid >> 3) + 32 * p;
                uint4 v = *reinterpret_cast<const uint4*>(
                    QKV + (rowbase + kt * 64 + row) * QSTR + hk + c * 8);
                *reinterpret_cast<uint4*>(KsB + row * 128 + ((c * 16) ^ ((row & 7) << 4))) = v;
            }
        }
        { // stage V^T [d][key]: key-pairs packed as u32, swizzled
            const int k2 = 2 * (tid & 31), dg = (tid >> 5) * 8;
            const unsigned short* va = QKV + (rowbase + kt * 64 + k2) * QSTR + hv + dg;
            unsigned short a8[8], b8[8];
            *reinterpret_cast<uint4*>(a8) = *reinterpret_cast<const uint4*>(va);
            *reinterpret_cast<uint4*>(b8) = *reinterpret_cast<const uint4*>(va + QSTR);
            #pragma unroll
            for (int i2 = 0; i2 < 8; ++i2) {
                unsigned int w = (unsigned)a8[i2] | ((unsigned)b8[i2] << 16);
                const int d = dg + i2;
                *reinterpret_cast<unsigned int*>(VTB + d * 128 + ((k2 * 2) ^ ((d & 7) << 4))) = w;
            }
        }
        __syncthreads();
        if (kt * 64 > wq + 31) continue;     // tile fully above diagonal for this wave

        // ---- S^T = K Q^T (8 mfma 32x32x16); scale pre-folded into Q
        f32x16 s0, s1;
        #pragma unroll
        for (int r = 0; r < 16; ++r) { s0[r] = 0.f; s1[r] = 0.f; }
        #pragma unroll
        for (int s = 0; s < 4; ++s) {
            const int off = (s * 32 + hi * 16) ^ ((lq & 7) << 4);
            bf16x8 k0 = *reinterpret_cast<const bf16x8*>(KsB + lq * 128 + off);
            bf16x8 k1 = *reinterpret_cast<const bf16x8*>(KsB + (lq + 32) * 128 + off);
            s0 = __builtin_amdgcn_mfma_f32_32x32x16_bf16(k0, qf[s], s0, 0, 0, 0);
            s1 = __builtin_amdgcn_mfma_f32_32x32x16_bf16(k1, qf[s], s1, 0, 0, 0);
        }

        // ---- causal mask (diagonal tiles only)
        const bool diag = (kt * 64 + 63) > wq;
        if (diag) {
            const int q_own = wq + lq;
            #pragma unroll
            for (int r = 0; r < 16; ++r) {
                const int kl = kt * 64 + (r & 3) + 8 * (r >> 2) + 4 * hi;
                if (kl > q_own) s0[r] = MASKVAL;
                if (kl + 32 > q_own) s1[r] = MASKVAL;
            }
        }

        // ---- in-register row max + pair exchange
        float pm = MASKVAL;
        #pragma unroll
        for (int r = 0; r < 16; ++r) pm = fmaxf(pm, fmaxf(s0[r], s1[r]));
        pm = fmaxf(pm, __shfl_xor(pm, 32));

        // ---- defer-max rescale (T13)
        if (__any(pm > mrow + DEFER_TH)) {
            const float mnew = fmaxf(mrow, pm);
            const float alpha = exp2f(mrow - mnew);
            #pragma unroll
            for (int r = 0; r < 16; ++r) { y0[r] *= alpha; y1[r] *= alpha; }
            lrow *= alpha;
            mrow = mnew;
        }
        // ---- exp2 + in-register row sum
        float sum = 0.f;
        #pragma unroll
        for (int r = 0; r < 16; ++r) {
            s0[r] = exp2f(s0[r] - mrow); sum += s0[r];
            s1[r] = exp2f(s1[r] - mrow); sum += s1[r];
        }
        sum += __shfl_xor(sum, 32);
        lrow += sum;

        // ---- Y^T += V^T P^T (8 mfma); P^T frags via pack+permlane32_swap
        PV_STEP(0, s0, 0)
        PV_STEP(1, s0, 8)
        PV_STEP(2, s1, 0)
        PV_STEP(3, s1, 8)
    }

    // ---- epilogue: normalize, transpose via per-wave LDS, coalesced store
    {
        const float inv = 1.f / lrow;
        char* ysb = (char*)&Ysc[wid][0];
        #pragma unroll
        for (int t = 0; t < 8; ++t) {
            const int dl = ((2 * t) & 3) + 8 * (t >> 1) + 4 * hi;
            unsigned int wa = pk2(y0[2 * t] * inv, y0[2 * t + 1] * inv);
            unsigned int wb = pk2(y1[2 * t] * inv, y1[2 * t + 1] * inv);
            *reinterpret_cast<unsigned int*>(ysb + lq * 144 + dl * 2) = wa;
            *reinterpret_cast<unsigned int*>(ysb + lq * 144 + (dl + 32) * 2) = wb;
        }
        #pragma unroll
        for (int u = 0; u < 4; ++u) {
            const int rr = lane >> 1, ch = (lane & 1) + 2 * u;
            uint4 val = *reinterpret_cast<const uint4*>(ysb + rr * 144 + ch * 16);
            *reinterpret_cast<uint4*>(Yb + (rowbase + q0 + wid * 32 + rr) * CDIM + h * DHEAD + ch * 8) = val;
        }
    }
}

// ---------------------------------------------------------------------------
extern "C" void kernel_launch(void* const* d_in, const int* in_sizes, int n_in,
                              void* d_out, int out_size, void* d_ws, size_t ws_size,
                              hipStream_t stream)
{
    const float* x  = (const float*)d_in[0];
    const float* Wk = (const float*)d_in[1];
    const float* bk = (const float*)d_in[2];
    const float* Wq = (const float*)d_in[3];
    const float* bq = (const float*)d_in[4];
    const float* Wv = (const float*)d_in[5];
    const float* bv = (const float*)d_in[6];
    const float* Wp = (const float*)d_in[7];
    const float* bp = (const float*)d_in[8];

    const size_t xe = (size_t)MROWS * CDIM;   // 8,388,608
    const size_t we = (size_t)CDIM * CDIM;    // 1,048,576
    unsigned short* xb    = (unsigned short*)d_ws;
    unsigned short* wqkvt = xb + xe;          // [3072][1024] = Wq^T|Wk^T|Wv^T
    unsigned short* wpt   = wqkvt + 3 * we;
    unsigned short* qkv   = wpt + we;         // [8192][3072] bf16
    unsigned short* ab    = qkv + (size_t)MROWS * QSTR;
    float*          bias3 = (float*)(ab + xe);

    cvt_x_kernel<<<(int)(xe / 8 / 256), 256, 0, stream>>>(x, xb);
    wt_kernel<<<dim3(32, 32, 4), 256, 0, stream>>>(
        Wq, Wk, Wv, Wp, wqkvt, wqkvt + we, wqkvt + 2 * we, wpt);
    pack_bias<<<12, 256, 0, stream>>>(bq, bk, bv, bias3);

    // fused QKV projection: [8192,1024] @ [1024,3072] + bias (q cols scaled)
    gemm_glds<0><<<24 * 64, 256, 0, stream>>>(xb, wqkvt, bias3, qkv,
                                              MROWS, QSTR, CDIM, 1024);

    attn_mfma3<<<dim3(16, NHEADS, BATCH), 256, 0, stream>>>(qkv, ab);

    // output projection -> fp32
    gemm_glds<1><<<8 * 64, 256, 0, stream>>>(ab, wpt, bp, d_out,
                                             MROWS, CDIM, CDIM, 0);
}

// Round 5
// 208.616 us; speedup vs baseline: 10.1829x; 1.1983x over previous
//
#include <hip/hip_runtime.h>
#include <hip/hip_bf16.h>

#define CDIM   1024
#define NHEADS 16
#define DHEAD  64
#define BATCH  4
#define TSEQ   2048
#define MROWS  (BATCH * TSEQ)
#define QSTR   3072                /* fused qkv row stride */
#define NEG_BIG (-1e30f)
#define MASKVAL (-3.0e38f)
#define SCALE_L2E 0.18033688011f   /* 0.125 * log2(e) */
#define DEFER_TH 11.5416f          /* 8 nats in log2 units */

typedef __attribute__((ext_vector_type(8)))  short bf16x8;
typedef __attribute__((ext_vector_type(4)))  float f32x4;
typedef __attribute__((ext_vector_type(16))) float f32x16;

__device__ __forceinline__ unsigned short f2bf(float f) {
    __hip_bfloat16 h = __float2bfloat16(f);
    return *reinterpret_cast<unsigned short*>(&h);
}
__device__ __forceinline__ unsigned int pk2(float a, float b) {
    return (unsigned)f2bf(a) | ((unsigned)f2bf(b) << 16);
}

// ---------------- x: fp32 -> bf16 (8 elems/thread) --------------------------
__global__ __launch_bounds__(256)
void cvt_x_kernel(const float* __restrict__ in, unsigned short* __restrict__ out)
{
    size_t i = (size_t)blockIdx.x * 256 + threadIdx.x;
    const float4* p = reinterpret_cast<const float4*>(in) + i * 2;
    float4 a = p[0], b = p[1];
    uint4 o;
    o.x = (unsigned)f2bf(a.x) | ((unsigned)f2bf(a.y) << 16);
    o.y = (unsigned)f2bf(a.z) | ((unsigned)f2bf(a.w) << 16);
    o.z = (unsigned)f2bf(b.x) | ((unsigned)f2bf(b.y) << 16);
    o.w = (unsigned)f2bf(b.z) | ((unsigned)f2bf(b.w) << 16);
    *reinterpret_cast<uint4*>(out + i * 8) = o;
}

// ---------------- W[K][N] fp32 -> W^T[N][K] bf16 (32x32 LDS tiles) ----------
__global__ __launch_bounds__(256)
void wt_kernel(const float* __restrict__ W0, const float* __restrict__ W1,
               const float* __restrict__ W2, const float* __restrict__ W3,
               unsigned short* __restrict__ T0, unsigned short* __restrict__ T1,
               unsigned short* __restrict__ T2, unsigned short* __restrict__ T3)
{
    const float* W; unsigned short* T;
    switch (blockIdx.z) {
        case 0:  W = W0; T = T0; break;
        case 1:  W = W1; T = T1; break;
        case 2:  W = W2; T = T2; break;
        default: W = W3; T = T3; break;
    }
    __shared__ float tile[32][33];
    const int t = threadIdx.x;
    const int r = t >> 3;
    const int c4 = (t & 7) * 4;
    const int n0 = blockIdx.x * 32, k0 = blockIdx.y * 32;
    float4 v = *reinterpret_cast<const float4*>(&W[(size_t)(k0 + r) * CDIM + n0 + c4]);
    tile[r][c4 + 0] = v.x; tile[r][c4 + 1] = v.y;
    tile[r][c4 + 2] = v.z; tile[r][c4 + 3] = v.w;
    __syncthreads();
    uint2 o;
    o.x = (unsigned)f2bf(tile[c4 + 0][r]) | ((unsigned)f2bf(tile[c4 + 1][r]) << 16);
    o.y = (unsigned)f2bf(tile[c4 + 2][r]) | ((unsigned)f2bf(tile[c4 + 3][r]) << 16);
    *reinterpret_cast<uint2*>(&T[(size_t)(n0 + r) * CDIM + k0 + c4]) = o;
}

// ---------------- bias concat [bq|bk|bv] ------------------------------------
__global__ __launch_bounds__(256)
void pack_bias(const float* __restrict__ bq, const float* __restrict__ bk,
               const float* __restrict__ bv, float* __restrict__ o)
{
    int i = blockIdx.x * 256 + threadIdx.x;   // 0..3071
    float v = (i < 1024) ? bq[i] : (i < 2048 ? bk[i - 1024] : bv[i - 2048]);
    o[i] = v;
}

// ---------------- m97-structure GEMM: C = A @ BT^T + bias, glds staging -----
template<int OUTMODE>
__global__ __launch_bounds__(256)
void gemm_glds(const unsigned short* __restrict__ A,
               const unsigned short* __restrict__ BT,
               const float* __restrict__ bias,
               void* __restrict__ Cout, int M, int N, int K, int nScaled)
{
    __shared__ __align__(16) unsigned short As[128 * 32];
    __shared__ __align__(16) unsigned short Bs[128 * 32];
    const int tid = threadIdx.x;
    const int nbn = N >> 7;
    const int bid = blockIdx.x;
    const int wg  = (bid & 7) * ((int)gridDim.x >> 3) + (bid >> 3);  // XCD swizzle
    const int n0  = (wg % nbn) * 128;
    const int m0  = (wg / nbn) * 128;

    const int lane = tid & 63, w = tid >> 6;
    const int wr = w >> 1, wc = w & 1;
    const int lj = lane & 15, lg = lane >> 4;
    const int rl = lane >> 2, sl = lane & 3;

    char* AsB = (char*)As;
    char* BsB = (char*)Bs;

    f32x4 acc[4][4];
    #pragma unroll
    for (int i = 0; i < 4; ++i)
        #pragma unroll
        for (int j = 0; j < 4; ++j) acc[i][j] = f32x4{0.f, 0.f, 0.f, 0.f};

    for (int k0 = 0; k0 < K; k0 += 32) {
        __syncthreads();
        #pragma unroll
        for (int t = 0; t < 2; ++t) {
            const int r = t * 64 + w * 16 + rl;
            const int g = sl ^ (r & 3);
            __builtin_amdgcn_global_load_lds(
                (const __attribute__((address_space(1))) void*)(A + (size_t)(m0 + r) * K + k0 + 8 * g),
                (__attribute__((address_space(3))) void*)(AsB + t * 4096 + w * 1024),
                16, 0, 0);
            __builtin_amdgcn_global_load_lds(
                (const __attribute__((address_space(1))) void*)(BT + (size_t)(n0 + r) * K + k0 + 8 * g),
                (__attribute__((address_space(3))) void*)(BsB + t * 4096 + w * 1024),
                16, 0, 0);
        }
        __syncthreads();
        bf16x8 af[4], bfr[4];
        #pragma unroll
        for (int i = 0; i < 4; ++i) {
            const int r = wr * 64 + i * 16 + lj;
            af[i] = *reinterpret_cast<const bf16x8*>(AsB + r * 64 + ((lg ^ (r & 3)) * 16));
        }
        #pragma unroll
        for (int j = 0; j < 4; ++j) {
            const int r = wc * 64 + j * 16 + lj;
            bfr[j] = *reinterpret_cast<const bf16x8*>(BsB + r * 64 + ((lg ^ (r & 3)) * 16));
        }
        #pragma unroll
        for (int i = 0; i < 4; ++i)
            #pragma unroll
            for (int j = 0; j < 4; ++j)
                acc[i][j] = __builtin_amdgcn_mfma_f32_16x16x32_bf16(af[i], bfr[j], acc[i][j], 0, 0, 0);
    }

    const float sc = (n0 < nScaled) ? SCALE_L2E : 1.0f;
    float bcol[4];
    #pragma unroll
    for (int j = 0; j < 4; ++j) bcol[j] = bias[n0 + wc * 64 + j * 16 + lj];

    #pragma unroll
    for (int i = 0; i < 4; ++i) {
        #pragma unroll
        for (int r4 = 0; r4 < 4; ++r4) {
            const int row = m0 + wr * 64 + i * 16 + lg * 4 + r4;
            #pragma unroll
            for (int j = 0; j < 4; ++j) {
                const int col = n0 + wc * 64 + j * 16 + lj;
                float v = (acc[i][j][r4] + bcol[j]) * sc;
                if (OUTMODE == 0)
                    reinterpret_cast<unsigned short*>(Cout)[(size_t)row * N + col] = f2bf(v);
                else
                    reinterpret_cast<float*>(Cout)[(size_t)row * N + col] = v;
            }
        }
    }
}

// ---------------- MFMA flash attention, swapped-QK 32x32 structure ----------
// 512 blocks, 4 waves x 32 q-rows = 128-row q-tile; block does balanced pair
// (p, 15-p) sequentially (uniform 34 KV-iterations). XCD-grouped id mapping:
// all 8 pair-blocks of one (h,b) share an XCD L2 (KV set = 4MB = one L2).
// KV double-buffered through registers: issue kt+1 loads before computing kt.
#define PV_STEP(m, T, rb) { \
    unsigned int w01 = pk2(T[(rb)+0], T[(rb)+1]); \
    unsigned int w23 = pk2(T[(rb)+2], T[(rb)+3]); \
    unsigned int w45 = pk2(T[(rb)+4], T[(rb)+5]); \
    unsigned int w67 = pk2(T[(rb)+6], T[(rb)+7]); \
    asm("v_permlane32_swap_b32 %0, %1" : "+v"(w01), "+v"(w45)); \
    asm("v_permlane32_swap_b32 %0, %1" : "+v"(w23), "+v"(w67)); \
    union { unsigned int u[4]; bf16x8 v; } pa; \
    pa.u[0] = w01; pa.u[1] = w23; pa.u[2] = w45; pa.u[3] = w67; \
    const int voff = (32 * (m) + 16 * hi) ^ ((lq & 7) << 4); \
    bf16x8 va = *reinterpret_cast<const bf16x8*>(VTB + lq * 128 + voff); \
    bf16x8 vb = *reinterpret_cast<const bf16x8*>(VTB + (lq + 32) * 128 + voff); \
    y0 = __builtin_amdgcn_mfma_f32_32x32x16_bf16(va, pa.v, y0, 0, 0, 0); \
    y1 = __builtin_amdgcn_mfma_f32_32x32x16_bf16(vb, pa.v, y1, 0, 0, 0); \
}

__global__ __launch_bounds__(256)
void attn_mfma4(const unsigned short* __restrict__ QKV, unsigned short* __restrict__ Yb)
{
    __shared__ unsigned short Ks[64 * 64];    // [key][d], swizzled
    __shared__ unsigned short VTs[64 * 64];   // [d][key], swizzled
    __shared__ unsigned short Ysc[4][32 * 72];// per-wave [q][d], 144B stride

    const int tid = threadIdx.x, lane = tid & 63, wid = tid >> 6;
    const int lq = lane & 31, hi = lane >> 5;

    // XCD-grouped decomposition: id%8 == hb%8 -> same (h,b) shares an XCD
    const int id  = blockIdx.x;
    const int kk  = id >> 3;
    const int hb  = (id & 7) + 8 * (kk >> 3);
    const int pair = kk & 7;
    const int h = hb & 15, bz = hb >> 4;

    const size_t rowbase = (size_t)bz * TSEQ;
    const int hq = h * DHEAD, hk = 1024 + h * DHEAD, hv = 2048 + h * DHEAD;
    char* KsB = (char*)Ks;
    char* VTB = (char*)VTs;

    // staging thread mapping (constant per thread)
    const int krow = tid >> 3;           // K rows krow, krow+32
    const int kswz = ((tid & 7) * 16) ^ ((krow & 7) << 4);
    const int vk2  = 2 * (tid & 31);     // V key-pair
    const int vdg  = (tid >> 5) * 8;     // V d-group

    for (int iter = 0; iter < 2; ++iter) {
        const int qtile = iter ? (15 - pair) : pair;
        const int q0 = qtile * 128;
        const int wq = q0 + wid * 32;

        bf16x8 qf[4];                            // Q^T B-frags: d = 16s + 8hi + j
        {
            const unsigned short* qp = QKV + (rowbase + wq + lq) * QSTR + hq + hi * 8;
            #pragma unroll
            for (int s = 0; s < 4; ++s)
                qf[s] = *reinterpret_cast<const bf16x8*>(qp + s * 16);
        }
        f32x16 y0, y1;                           // Y^T tiles: d 0..31 / 32..63
        #pragma unroll
        for (int r = 0; r < 16; ++r) { y0[r] = 0.f; y1[r] = 0.f; }
        float mrow = NEG_BIG, lrow = 0.f;

        const int ktend = 2 * qtile + 2;

        // prefetch tile 0 into registers
        uint4 kr0, kr1, vr0, vr1;
        {
            const unsigned short* kp = QKV + (rowbase + krow) * QSTR + hk + (tid & 7) * 8;
            kr0 = *reinterpret_cast<const uint4*>(kp);
            kr1 = *reinterpret_cast<const uint4*>(kp + 32 * QSTR);
            const unsigned short* vp = QKV + (rowbase + vk2) * QSTR + hv + vdg;
            vr0 = *reinterpret_cast<const uint4*>(vp);
            vr1 = *reinterpret_cast<const uint4*>(vp + QSTR);
        }

        for (int kt = 0; kt < ktend; ++kt) {
            __syncthreads();                     // previous tile's consumers done
            // ---- write prefetched regs -> LDS (K swizzled, V^T pair-packed)
            *reinterpret_cast<uint4*>(KsB + krow * 128 + kswz) = kr0;
            *reinterpret_cast<uint4*>(KsB + (krow + 32) * 128 + kswz) = kr1;
            {
                unsigned short a8[8], b8[8];
                *reinterpret_cast<uint4*>(a8) = vr0;
                *reinterpret_cast<uint4*>(b8) = vr1;
                #pragma unroll
                for (int i2 = 0; i2 < 8; ++i2) {
                    unsigned int w = (unsigned)a8[i2] | ((unsigned)b8[i2] << 16);
                    const int d = vdg + i2;
                    *reinterpret_cast<unsigned int*>(VTB + d * 128 + ((vk2 * 2) ^ ((d & 7) << 4))) = w;
                }
            }
            __syncthreads();                     // LDS tile ready

            // ---- issue next tile's global loads (latency hides under compute)
            if (kt + 1 < ktend) {
                const unsigned short* kp = QKV + (rowbase + (kt + 1) * 64 + krow) * QSTR + hk + (tid & 7) * 8;
                kr0 = *reinterpret_cast<const uint4*>(kp);
                kr1 = *reinterpret_cast<const uint4*>(kp + 32 * QSTR);
                const unsigned short* vp = QKV + (rowbase + (kt + 1) * 64 + vk2) * QSTR + hv + vdg;
                vr0 = *reinterpret_cast<const uint4*>(vp);
                vr1 = *reinterpret_cast<const uint4*>(vp + QSTR);
            }

            if (kt * 64 > wq + 31) continue;     // tile above diagonal for this wave

            // ---- S^T = K Q^T (8 mfma 32x32x16); scale pre-folded into Q
            f32x16 s0, s1;
            #pragma unroll
            for (int r = 0; r < 16; ++r) { s0[r] = 0.f; s1[r] = 0.f; }
            #pragma unroll
            for (int s = 0; s < 4; ++s) {
                const int off = (s * 32 + hi * 16) ^ ((lq & 7) << 4);
                bf16x8 k0 = *reinterpret_cast<const bf16x8*>(KsB + lq * 128 + off);
                bf16x8 k1 = *reinterpret_cast<const bf16x8*>(KsB + (lq + 32) * 128 + off);
                s0 = __builtin_amdgcn_mfma_f32_32x32x16_bf16(k0, qf[s], s0, 0, 0, 0);
                s1 = __builtin_amdgcn_mfma_f32_32x32x16_bf16(k1, qf[s], s1, 0, 0, 0);
            }

            // ---- causal mask (diagonal tiles only)
            const bool diag = (kt * 64 + 63) > wq;
            if (diag) {
                const int q_own = wq + lq;
                #pragma unroll
                for (int r = 0; r < 16; ++r) {
                    const int kl = kt * 64 + (r & 3) + 8 * (r >> 2) + 4 * hi;
                    if (kl > q_own) s0[r] = MASKVAL;
                    if (kl + 32 > q_own) s1[r] = MASKVAL;
                }
            }

            // ---- in-register row max + pair exchange
            float pm = MASKVAL;
            #pragma unroll
            for (int r = 0; r < 16; ++r) pm = fmaxf(pm, fmaxf(s0[r], s1[r]));
            pm = fmaxf(pm, __shfl_xor(pm, 32));

            // ---- defer-max rescale (T13)
            if (__any(pm > mrow + DEFER_TH)) {
                const float mnew = fmaxf(mrow, pm);
                const float alpha = exp2f(mrow - mnew);
                #pragma unroll
                for (int r = 0; r < 16; ++r) { y0[r] *= alpha; y1[r] *= alpha; }
                lrow *= alpha;
                mrow = mnew;
            }
            // ---- exp2 + in-register row sum
            float sum = 0.f;
            #pragma unroll
            for (int r = 0; r < 16; ++r) {
                s0[r] = exp2f(s0[r] - mrow); sum += s0[r];
                s1[r] = exp2f(s1[r] - mrow); sum += s1[r];
            }
            sum += __shfl_xor(sum, 32);
            lrow += sum;

            // ---- Y^T += V^T P^T (8 mfma); P^T frags via pack+permlane32_swap
            PV_STEP(0, s0, 0)
            PV_STEP(1, s0, 8)
            PV_STEP(2, s1, 0)
            PV_STEP(3, s1, 8)
        }

        // ---- epilogue: normalize, transpose via per-wave LDS, coalesced store
        {
            const float inv = 1.f / lrow;
            char* ysb = (char*)&Ysc[wid][0];
            #pragma unroll
            for (int t = 0; t < 8; ++t) {
                const int dl = ((2 * t) & 3) + 8 * (t >> 1) + 4 * hi;
                unsigned int wa = pk2(y0[2 * t] * inv, y0[2 * t + 1] * inv);
                unsigned int wb = pk2(y1[2 * t] * inv, y1[2 * t + 1] * inv);
                *reinterpret_cast<unsigned int*>(ysb + lq * 144 + dl * 2) = wa;
                *reinterpret_cast<unsigned int*>(ysb + lq * 144 + (dl + 32) * 2) = wb;
            }
            #pragma unroll
            for (int u = 0; u < 4; ++u) {
                const int rr = lane >> 1, ch = (lane & 1) + 2 * u;
                uint4 val = *reinterpret_cast<const uint4*>(ysb + rr * 144 + ch * 16);
                *reinterpret_cast<uint4*>(Yb + (rowbase + q0 + wid * 32 + rr) * CDIM + h * DHEAD + ch * 8) = val;
            }
        }
    }
}

// ---------------------------------------------------------------------------
extern "C" void kernel_launch(void* const* d_in, const int* in_sizes, int n_in,
                              void* d_out, int out_size, void* d_ws, size_t ws_size,
                              hipStream_t stream)
{
    const float* x  = (const float*)d_in[0];
    const float* Wk = (const float*)d_in[1];
    const float* bk = (const float*)d_in[2];
    const float* Wq = (const float*)d_in[3];
    const float* bq = (const float*)d_in[4];
    const float* Wv = (const float*)d_in[5];
    const float* bv = (const float*)d_in[6];
    const float* Wp = (const float*)d_in[7];
    const float* bp = (const float*)d_in[8];

    const size_t xe = (size_t)MROWS * CDIM;   // 8,388,608
    const size_t we = (size_t)CDIM * CDIM;    // 1,048,576
    unsigned short* xb    = (unsigned short*)d_ws;
    unsigned short* wqkvt = xb + xe;          // [3072][1024] = Wq^T|Wk^T|Wv^T
    unsigned short* wpt   = wqkvt + 3 * we;
    unsigned short* qkv   = wpt + we;         // [8192][3072] bf16
    unsigned short* ab    = qkv + (size_t)MROWS * QSTR;
    float*          bias3 = (float*)(ab + xe);

    cvt_x_kernel<<<(int)(xe / 8 / 256), 256, 0, stream>>>(x, xb);
    wt_kernel<<<dim3(32, 32, 4), 256, 0, stream>>>(
        Wq, Wk, Wv, Wp, wqkvt, wqkvt + we, wqkvt + 2 * we, wpt);
    pack_bias<<<12, 256, 0, stream>>>(bq, bk, bv, bias3);

    // fused QKV projection: [8192,1024] @ [1024,3072] + bias (q cols scaled)
    gemm_glds<0><<<24 * 64, 256, 0, stream>>>(xb, wqkvt, bias3, qkv,
                                              MROWS, QSTR, CDIM, 1024);

    attn_mfma4<<<512, 256, 0, stream>>>(qkv, ab);

    // output projection -> fp32
    gemm_glds<1><<<8 * 64, 256, 0, stream>>>(ab, wpt, bp, d_out,
                                             MROWS, CDIM, CDIM, 0);
}